// Round 7
// baseline (137.867 us; speedup 1.0000x reference)
//
#include <hip/hip_runtime.h>

#define HW 28
#define NPIX 784
#define NB 512
#define PADW2 34                 // row stride in float2 (cols -3..30), 272 B
#define PADH 34                  // rows -3..30
#define IMG_F2 (PADH * PADW2)    // 1156 float2 = 9248 B per image

typedef float v2f __attribute__((ext_vector_type(2)));

// ---------------------------------------------------------------------------
// 7x2 output tile per thread. Per row: 4 ds_read_b128 (8 float2 taps).
// Weights are preloaded from LDS into a VGPR-resident W[49]: LDS reads cannot
// be scalarized to s_load (round-6 lesson: uniform GLOBAL weight reads became
// in-loop s_loads whose SMEM/DS shared-lgkmcnt drains serialized the K-loop).
// ---------------------------------------------------------------------------
__device__ __forceinline__ void conv2col(const float2* sbuf,
                                         const float2* wlds,   // LDS, 49 float2
                                         int R0, int c, float o0[7], float o1[7])
{
    v2f W[49];
    {
        const float4* wp = (const float4*)wlds;    // broadcast, conflict-free
#pragma unroll
        for (int k = 0; k < 24; ++k) {
            float4 q = wp[k];
            W[2 * k]     = (v2f){q.x, q.y};
            W[2 * k + 1] = (v2f){q.z, q.w};
        }
        float2 lastw = wlds[48];
        W[48] = (v2f){lastw.x, lastw.y};
    }

    v2f   sN0[7], sN1[7];
    float sD0[7], sD1[7];
#pragma unroll
    for (int r = 0; r < 7; ++r) {
        sN0[r] = (v2f){0.f, 0.f}; sN1[r] = (v2f){0.f, 0.f};
        sD0[r] = 0.f; sD1[r] = 0.f;
    }
#pragma unroll
    for (int rr = 0; rr < 13; ++rr) {
        const float4* rq = (const float4*)(sbuf + (R0 + rr) * PADW2 + 2 * c);
        float4 q0 = rq[0], q1 = rq[1], q2 = rq[2], q3 = rq[3];
        v2f tp[8];
        tp[0] = (v2f){q0.x, q0.y}; tp[1] = (v2f){q0.z, q0.w};
        tp[2] = (v2f){q1.x, q1.y}; tp[3] = (v2f){q1.z, q1.w};
        tp[4] = (v2f){q2.x, q2.y}; tp[5] = (v2f){q2.z, q2.w};
        tp[6] = (v2f){q3.x, q3.y}; tp[7] = (v2f){q3.z, q3.w};
#pragma unroll
        for (int r = 0; r < 7; ++r) {
            if (r > rr || rr - r > 6) continue;     // compile-time fold
            const int di = rr - r;
#pragma unroll
            for (int t = 0; t < 7; ++t) {
                v2f wq = W[di * 7 + t];             // (qw, ew) in VGPRs
                sN0[r] = __builtin_elementwise_fma(tp[t],     wq, sN0[r]);
                sN1[r] = __builtin_elementwise_fma(tp[t + 1], wq, sN1[r]);
                sD0[r] = fmaf(tp[t][0],     wq[1], sD0[r]);
                sD1[r] = fmaf(tp[t + 1][0], wq[1], sD1[r]);
            }
        }
    }
#pragma unroll
    for (int r = 0; r < 7; ++r) {
        o0[r] = (sN0[r][0] + sN0[r][1]) * __builtin_amdgcn_rcpf(sD0[r]);
        o1[r] = (sN1[r][0] + sN1[r][1]) * __builtin_amdgcn_rcpf(sD1[r]);
    }
}

// ---------------------------------------------------------------------------
// Fused smorph x2 + 4x4 mean pool. 4 image-pure waves/block, in-place evpv.
// Per-block weight table computed in-kernel into LDS (no setup kernel, no
// global wtab). waves_per_eu(2,2): allocator budget 256 VGPR, so W[49]+acc
// stay register-resident (2 waves/SIMD, 2 blocks/CU by VGPR).
// ---------------------------------------------------------------------------
__global__
__attribute__((amdgpu_flat_work_group_size(256, 256)))
__attribute__((amdgpu_waves_per_eu(2, 2)))
void smorph_fused_kernel(
    const float* __restrict__ x,       // [512,784]
    const float* __restrict__ sw,      // [8,2,49]
    const float* __restrict__ sa,      // [8,2]
    float* __restrict__ feat)          // [512,392]
{
    __shared__ __align__(16) float2 evpv[4][IMG_F2];   // 36,992 B
    __shared__ __align__(16) float2 wlds[2][49];       //    784 B

    const int bx   = blockIdx.x;       // 1024 blocks = 8 f x 128 quads
    const int f    = bx >> 7;
    const int bq   = bx & 127;
    const int tid  = threadIdx.x;
    const int wv   = tid >> 6;         // wave -> image
    const int lane = tid & 63;
    const int b    = bq * 4 + wv;

    const float a1 = sa[f * 2 + 0];
    const float a2 = sa[f * 2 + 1];

    // weight table: (qw, ew) = (w*e^{aw}, e^{aw}) for both stages of this f
    if (tid < 98) {
        int s = tid / 49;              // stage
        int t = tid - s * 49;
        float a  = sa[f * 2 + s];
        float w  = sw[(f * 2 + s) * 49 + t];
        float e  = __expf(a * w);
        wlds[s][t] = make_float2(w * e, e);
    }

    float2* buf = evpv[wv];

    // Phase 0: padded (ev,pv) for stage 1; borders (1,0)  (SAME zero-pad)
    const float* src = x + (size_t)b * NPIX;
    for (int idx = lane; idx < IMG_F2; idx += 64) {
        int pi = idx / PADW2;
        int pj = idx - pi * PADW2;
        float2 val = make_float2(1.f, 0.f);
        if (pi >= 3 && pi < 31 && pj >= 3 && pj < 31) {
            float v = src[(pi - 3) * HW + (pj - 3)];
            float e = __expf(a1 * v);
            val = make_float2(e, v * e);
        }
        buf[idx] = val;
    }
    __syncthreads();

    const bool act = (lane < 56);
    const int s  = lane / 14;          // strip 0..3 (output rows 7s..7s+6)
    const int c  = lane - s * 14;      // column pair 0..13
    const int R0 = 7 * s;
    const int j2 = 2 * c;

    float o0[7], o1[7];
    if (act) conv2col(buf, wlds[0], R0, c, o0, o1);
    __syncthreads();                   // all stage-1 reads complete

    // Phase 2: overwrite interior with stage-2 (ev,pv); borders stay (1,0)
    if (act) {
#pragma unroll
        for (int r = 0; r < 7; ++r) {
            float e0 = __expf(a2 * o0[r]);
            float e1 = __expf(a2 * o1[r]);
            buf[(R0 + r + 3) * PADW2 + (j2 + 3)] = make_float2(e0, o0[r] * e0);
            buf[(R0 + r + 3) * PADW2 + (j2 + 4)] = make_float2(e1, o1[r] * e1);
        }
    }
    __syncthreads();

    if (act) conv2col(buf, wlds[1], R0, c, o0, o1);
    __syncthreads();                   // all stage-2 reads complete

    // Phase 4: dense 28x28 float plane (aliases buf; reads are done)
    float* outp = (float*)buf;
    if (act) {
#pragma unroll
        for (int r = 0; r < 7; ++r) {
            outp[(R0 + r) * HW + j2]     = o0[r];
            outp[(R0 + r) * HW + j2 + 1] = o1[r];
        }
    }
    __syncthreads();

    // Phase 5: 4x4 mean pool -> feat[b, f*49 + t]
    if (lane < 49) {
        int pi = lane / 7;
        int pj = lane - pi * 7;
        float sum = 0.f;
#pragma unroll
        for (int di = 0; di < 4; ++di)
#pragma unroll
            for (int dj = 0; dj < 4; ++dj)
                sum += outp[(pi * 4 + di) * HW + (pj * 4 + dj)];
        feat[(size_t)b * 392 + f * 49 + lane] = sum * 0.0625f;
    }
}

// ---------------------------------------------------------------------------
// MLP 392->120->84->10, sigmoid. One block per batch row; dots split across
// lanes with component-parallel accumulators + shuffle reduce.
// ---------------------------------------------------------------------------
__device__ __forceinline__ float sigmoidf_(float s) {
    return __builtin_amdgcn_rcpf(1.f + __expf(-s));
}

__global__ __launch_bounds__(256) void mlp_kernel(
    const float* __restrict__ feat,
    const float* __restrict__ W1, const float* __restrict__ b1,
    const float* __restrict__ W2, const float* __restrict__ b2,
    const float* __restrict__ W3, const float* __restrict__ b3,
    float* __restrict__ out)
{
    __shared__ __align__(16) float fsh[392];
    __shared__ __align__(16) float h1[120];
    __shared__ __align__(16) float h2[84];
    const int b   = blockIdx.x;
    const int tid = threadIdx.x;

    if (tid < 98)
        ((float4*)fsh)[tid] = ((const float4*)(feat + (size_t)b * 392))[tid];
    __syncthreads();

    if (tid < 240) {
        int n = tid >> 1, h = tid & 1;
        const float4* wr = (const float4*)(W1 + n * 392);
        const float4* fv = (const float4*)fsh;
        float c0 = 0.f, c1 = 0.f, c2 = 0.f, c3 = 0.f;
#pragma unroll 7
        for (int k = h; k < 98; k += 2) {
            float4 w = wr[k];
            float4 v = fv[k];
            c0 = fmaf(w.x, v.x, c0);
            c1 = fmaf(w.y, v.y, c1);
            c2 = fmaf(w.z, v.z, c2);
            c3 = fmaf(w.w, v.w, c3);
        }
        float acc = (c0 + c1) + (c2 + c3);
        acc += __shfl_xor(acc, 1);
        if (h == 0) h1[n] = sigmoidf_(acc + b1[n]);
    }
    __syncthreads();

    if (tid < 168) {
        int n = tid >> 1, h = tid & 1;
        const float4* wr = (const float4*)(W2 + n * 120);
        const float4* hv = (const float4*)h1;
        float c0 = 0.f, c1 = 0.f, c2 = 0.f, c3 = 0.f;
#pragma unroll
        for (int k = h; k < 30; k += 2) {
            float4 w = wr[k];
            float4 v = hv[k];
            c0 = fmaf(w.x, v.x, c0);
            c1 = fmaf(w.y, v.y, c1);
            c2 = fmaf(w.z, v.z, c2);
            c3 = fmaf(w.w, v.w, c3);
        }
        float acc = (c0 + c1) + (c2 + c3);
        acc += __shfl_xor(acc, 1);
        if (h == 0) h2[n] = sigmoidf_(acc + b2[n]);
    }
    __syncthreads();

    if (tid < 40) {
        int n = tid >> 2, q = tid & 3;
        const float4* wr = (const float4*)(W3 + n * 84);
        const float4* hv = (const float4*)h2;
        float c0 = 0.f, c1 = 0.f, c2 = 0.f, c3 = 0.f;
        for (int k = q; k < 21; k += 4) {
            float4 w = wr[k];
            float4 v = hv[k];
            c0 = fmaf(w.x, v.x, c0);
            c1 = fmaf(w.y, v.y, c1);
            c2 = fmaf(w.z, v.z, c2);
            c3 = fmaf(w.w, v.w, c3);
        }
        float acc = (c0 + c1) + (c2 + c3);
        acc += __shfl_xor(acc, 1);
        acc += __shfl_xor(acc, 2);
        if (q == 0) out[(size_t)b * 10 + n] = sigmoidf_(acc + b3[n]);
    }
}

extern "C" void kernel_launch(void* const* d_in, const int* in_sizes, int n_in,
                              void* d_out, int out_size, void* d_ws, size_t ws_size,
                              hipStream_t stream) {
    const float* x  = (const float*)d_in[0];
    const float* sw = (const float*)d_in[1];
    const float* sa = (const float*)d_in[2];
    const float* W1 = (const float*)d_in[3];
    const float* b1 = (const float*)d_in[4];
    const float* W2 = (const float*)d_in[5];
    const float* b2 = (const float*)d_in[6];
    const float* W3 = (const float*)d_in[7];
    const float* b3 = (const float*)d_in[8];
    float* out = (float*)d_out;

    float* feat = (float*)d_ws;                    // 512*392 floats

    smorph_fused_kernel<<<1024, 256, 0, stream>>>(x, sw, sa, feat);
    mlp_kernel<<<NB, 256, 0, stream>>>(feat, W1, b1, W2, b2, W3, b3, out);
}

// Round 8
// 125.757 us; speedup vs baseline: 1.0963x; 1.0963x over previous
//
#include <hip/hip_runtime.h>

#define HW 28
#define NPIX 784
#define NB 512
#define PADW2 34                 // row stride in float2 (cols -3..30)
#define PADH 34                  // rows -3..30
#define IMG_F2 (PADH * PADW2)    // 1156 float2 = 9248 B per buffer

typedef float v2f __attribute__((ext_vector_type(2)));

// ---------------------------------------------------------------------------
// 7x2 output tile per thread. Per row: 4 ds_read_b128 (8 float2 taps).
// W[49] preloaded from LDS into VGPRs — at budget 256 (see kernel attrs)
// it stays resident; rounds 5-7 showed budget 128 forces in-loop remat.
// ---------------------------------------------------------------------------
__device__ __forceinline__ void conv2col(const float2* sbuf,
                                         const float2* wlds,   // LDS, 49 float2
                                         int R0, int c, float o0[7], float o1[7])
{
    v2f W[49];
    {
        const float4* wp = (const float4*)wlds;    // broadcast, conflict-free
#pragma unroll
        for (int k = 0; k < 24; ++k) {
            float4 q = wp[k];
            W[2 * k]     = (v2f){q.x, q.y};
            W[2 * k + 1] = (v2f){q.z, q.w};
        }
        float2 lastw = wlds[48];
        W[48] = (v2f){lastw.x, lastw.y};
    }

    v2f   sN0[7], sN1[7];
    float sD0[7], sD1[7];
#pragma unroll
    for (int r = 0; r < 7; ++r) {
        sN0[r] = (v2f){0.f, 0.f}; sN1[r] = (v2f){0.f, 0.f};
        sD0[r] = 0.f; sD1[r] = 0.f;
    }
#pragma unroll
    for (int rr = 0; rr < 13; ++rr) {
        const float4* rq = (const float4*)(sbuf + (R0 + rr) * PADW2 + 2 * c);
        float4 q0 = rq[0], q1 = rq[1], q2 = rq[2], q3 = rq[3];
        v2f tp[8];
        tp[0] = (v2f){q0.x, q0.y}; tp[1] = (v2f){q0.z, q0.w};
        tp[2] = (v2f){q1.x, q1.y}; tp[3] = (v2f){q1.z, q1.w};
        tp[4] = (v2f){q2.x, q2.y}; tp[5] = (v2f){q2.z, q2.w};
        tp[6] = (v2f){q3.x, q3.y}; tp[7] = (v2f){q3.z, q3.w};
#pragma unroll
        for (int r = 0; r < 7; ++r) {
            if (r > rr || rr - r > 6) continue;     // compile-time fold
            const int di = rr - r;
#pragma unroll
            for (int t = 0; t < 7; ++t) {
                v2f wq = W[di * 7 + t];             // (qw, ew) in VGPRs
                sN0[r] = __builtin_elementwise_fma(tp[t],     wq, sN0[r]);
                sN1[r] = __builtin_elementwise_fma(tp[t + 1], wq, sN1[r]);
                sD0[r] = fmaf(tp[t][0],     wq[1], sD0[r]);
                sD1[r] = fmaf(tp[t + 1][0], wq[1], sD1[r]);
            }
        }
    }
#pragma unroll
    for (int r = 0; r < 7; ++r) {
        o0[r] = (sN0[r][0] + sN0[r][1]) * __builtin_amdgcn_rcpf(sD0[r]);
        o1[r] = (sN1[r][0] + sN1[r][1]) * __builtin_amdgcn_rcpf(sD1[r]);
    }
}

// ---------------------------------------------------------------------------
// Fused smorph x2 + 4x4 mean pool. ONE WAVE PER IMAGE, 64-thread blocks,
// ZERO barriers (all ordering is wave-internal program order + lgkmcnt).
// LDS = 19,280 B/block -> 8 blocks/CU = 8 waves/CU = 2 waves/SIMD, which
// makes the backend's LDS-derived VGPR budget 512/2 = 256 so W[49] (98
// VGPRs) stays register-resident (rounds 2-7 data: budget = 512/waves_per_
// SIMD derived from LDS; at budget 128 the compiler remats W in-loop).
// ---------------------------------------------------------------------------
__global__
__attribute__((amdgpu_flat_work_group_size(64, 64)))
__attribute__((amdgpu_waves_per_eu(2, 2)))
void smorph_fused_kernel(
    const float* __restrict__ x,       // [512,784]
    const float* __restrict__ sw,      // [8,2,49]
    const float* __restrict__ sa,      // [8,2]
    float* __restrict__ feat)          // [512,392]
{
    __shared__ __align__(16) float2 buf1[IMG_F2];  // stage-1 evpv
    __shared__ __align__(16) float2 buf2[IMG_F2];  // stage-2 evpv
    __shared__ __align__(16) float2 wtab[2][49];   // this block's weights

    const int bx   = blockIdx.x;       // 4096 blocks = 8 f x 512 b
    const int f    = bx >> 9;
    const int b    = bx & 511;
    const int lane = threadIdx.x;      // 0..63

    const float a1 = sa[f * 2 + 0];
    const float a2 = sa[f * 2 + 1];

    // Weight table: (qw, ew) = (w*e^{aw}, e^{aw}) for both stages
    if (lane < 49) {
        float w1 = sw[(f * 2 + 0) * 49 + lane];
        float e1 = __expf(a1 * w1);
        wtab[0][lane] = make_float2(w1 * e1, e1);
        float w2 = sw[(f * 2 + 1) * 49 + lane];
        float e2 = __expf(a2 * w2);
        wtab[1][lane] = make_float2(w2 * e2, e2);
    }

    // Phase 0: buf1 = padded (ev,pv) of x; borders of BOTH buffers = (1,0)
    const float* src = x + (size_t)b * NPIX;
    {
        int pi = lane / PADW2;
        int pj = lane - pi * PADW2;
        for (int idx = lane; idx < IMG_F2; idx += 64) {
            if (pi >= 3 && pi < 31 && pj >= 3 && pj < 31) {
                float v = src[(pi - 3) * HW + (pj - 3)];
                float e = __expf(a1 * v);
                buf1[idx] = make_float2(e, v * e);
            } else {
                buf1[idx] = make_float2(1.f, 0.f);
                buf2[idx] = make_float2(1.f, 0.f);
            }
            pi += 1; pj += 30;                  // advance by 64 = 34 + 30
            if (pj >= PADW2) { pj -= PADW2; pi += 1; }
        }
    }

    const bool act = (lane < 56);
    const int s  = lane / 14;          // strip 0..3 (output rows 7s..7s+6)
    const int c  = lane - s * 14;      // column pair 0..13
    const int R0 = 7 * s;
    const int j2 = 2 * c;

    // Stage 1 conv (reads buf1; wave-internal ordering, no barrier)
    float o0[7], o1[7];
    if (act) conv2col(buf1, wtab[0], R0, c, o0, o1);

    // Stage-2 (ev,pv) into buf2 interior
    if (act) {
#pragma unroll
        for (int r = 0; r < 7; ++r) {
            float e0 = __expf(a2 * o0[r]);
            float e1 = __expf(a2 * o1[r]);
            buf2[(R0 + r + 3) * PADW2 + (j2 + 3)] = make_float2(e0, o0[r] * e0);
            buf2[(R0 + r + 3) * PADW2 + (j2 + 4)] = make_float2(e1, o1[r] * e1);
        }
    }

    // Stage 2 conv (reads buf2)
    if (act) conv2col(buf2, wtab[1], R0, c, o0, o1);

    // Dense 28x28 output plane aliased over buf1 (conv1 reads are done)
    float* outp = (float*)buf1;
    if (act) {
#pragma unroll
        for (int r = 0; r < 7; ++r) {
            outp[(R0 + r) * HW + j2]     = o0[r];
            outp[(R0 + r) * HW + j2 + 1] = o1[r];
        }
    }

    // 4x4 mean pool -> feat[b, f*49 + t]
    if (lane < 49) {
        int pi = lane / 7;
        int pj = lane - pi * 7;
        float sum = 0.f;
#pragma unroll
        for (int di = 0; di < 4; ++di)
#pragma unroll
            for (int dj = 0; dj < 4; ++dj)
                sum += outp[(pi * 4 + di) * HW + (pj * 4 + dj)];
        feat[(size_t)b * 392 + f * 49 + lane] = sum * 0.0625f;
    }
}

// ---------------------------------------------------------------------------
// MLP 392->120->84->10, sigmoid. One block per batch row; dots split across
// lanes with component-parallel accumulators + shuffle reduce.
// ---------------------------------------------------------------------------
__device__ __forceinline__ float sigmoidf_(float s) {
    return __builtin_amdgcn_rcpf(1.f + __expf(-s));
}

__global__ __launch_bounds__(256) void mlp_kernel(
    const float* __restrict__ feat,
    const float* __restrict__ W1, const float* __restrict__ b1,
    const float* __restrict__ W2, const float* __restrict__ b2,
    const float* __restrict__ W3, const float* __restrict__ b3,
    float* __restrict__ out)
{
    __shared__ __align__(16) float fsh[392];
    __shared__ __align__(16) float h1[120];
    __shared__ __align__(16) float h2[84];
    const int b   = blockIdx.x;
    const int tid = threadIdx.x;

    if (tid < 98)
        ((float4*)fsh)[tid] = ((const float4*)(feat + (size_t)b * 392))[tid];
    __syncthreads();

    if (tid < 240) {
        int n = tid >> 1, h = tid & 1;
        const float4* wr = (const float4*)(W1 + n * 392);
        const float4* fv = (const float4*)fsh;
        float c0 = 0.f, c1 = 0.f, c2 = 0.f, c3 = 0.f;
#pragma unroll 7
        for (int k = h; k < 98; k += 2) {
            float4 w = wr[k];
            float4 v = fv[k];
            c0 = fmaf(w.x, v.x, c0);
            c1 = fmaf(w.y, v.y, c1);
            c2 = fmaf(w.z, v.z, c2);
            c3 = fmaf(w.w, v.w, c3);
        }
        float acc = (c0 + c1) + (c2 + c3);
        acc += __shfl_xor(acc, 1);
        if (h == 0) h1[n] = sigmoidf_(acc + b1[n]);
    }
    __syncthreads();

    if (tid < 168) {
        int n = tid >> 1, h = tid & 1;
        const float4* wr = (const float4*)(W2 + n * 120);
        const float4* hv = (const float4*)h1;
        float c0 = 0.f, c1 = 0.f, c2 = 0.f, c3 = 0.f;
#pragma unroll
        for (int k = h; k < 30; k += 2) {
            float4 w = wr[k];
            float4 v = hv[k];
            c0 = fmaf(w.x, v.x, c0);
            c1 = fmaf(w.y, v.y, c1);
            c2 = fmaf(w.z, v.z, c2);
            c3 = fmaf(w.w, v.w, c3);
        }
        float acc = (c0 + c1) + (c2 + c3);
        acc += __shfl_xor(acc, 1);
        if (h == 0) h2[n] = sigmoidf_(acc + b2[n]);
    }
    __syncthreads();

    if (tid < 40) {
        int n = tid >> 2, q = tid & 3;
        const float4* wr = (const float4*)(W3 + n * 84);
        const float4* hv = (const float4*)h2;
        float c0 = 0.f, c1 = 0.f, c2 = 0.f, c3 = 0.f;
        for (int k = q; k < 21; k += 4) {
            float4 w = wr[k];
            float4 v = hv[k];
            c0 = fmaf(w.x, v.x, c0);
            c1 = fmaf(w.y, v.y, c1);
            c2 = fmaf(w.z, v.z, c2);
            c3 = fmaf(w.w, v.w, c3);
        }
        float acc = (c0 + c1) + (c2 + c3);
        acc += __shfl_xor(acc, 1);
        acc += __shfl_xor(acc, 2);
        if (q == 0) out[(size_t)b * 10 + n] = sigmoidf_(acc + b3[n]);
    }
}

extern "C" void kernel_launch(void* const* d_in, const int* in_sizes, int n_in,
                              void* d_out, int out_size, void* d_ws, size_t ws_size,
                              hipStream_t stream) {
    const float* x  = (const float*)d_in[0];
    const float* sw = (const float*)d_in[1];
    const float* sa = (const float*)d_in[2];
    const float* W1 = (const float*)d_in[3];
    const float* b1 = (const float*)d_in[4];
    const float* W2 = (const float*)d_in[5];
    const float* b2 = (const float*)d_in[6];
    const float* W3 = (const float*)d_in[7];
    const float* b3 = (const float*)d_in[8];
    float* out = (float*)d_out;

    float* feat = (float*)d_ws;                    // 512*392 floats

    smorph_fused_kernel<<<4096, 64, 0, stream>>>(x, sw, sa, feat);
    mlp_kernel<<<NB, 256, 0, stream>>>(feat, W1, b1, W2, b2, W3, b3, out);
}